// Round 2
// baseline (164.833 us; speedup 1.0000x reference)
//
#include <hip/hip_runtime.h>
#include <math.h>

// Bit-exact replication of the numpy fp32 reference requires mul/add with
// separate rounding (no FMA contraction): the entry-face validity test
// (pos > -1) is knife-edge for every hitting ray.
#pragma clang fp contract(off)

#define DT 0.03125f
#define NSTEPS 111

__device__ __forceinline__ float4 lerp4(float4 a, float4 b, float w) {
#pragma clang fp contract(off)
    float wa = 1.0f - w;
    float4 r;
    r.x = a.x * wa + b.x * w;
    r.y = a.y * wa + b.y * w;
    r.z = a.z * wa + b.z * w;
    r.w = a.w * wa + b.w * w;
    return r;
}

// Repack volume [B,4,D,H,W] -> [B,D,H,W,4] so one voxel's 4 channels are a single float4.
__global__ __launch_bounds__(256) void repack_kernel(const float* __restrict__ vol,
                                                     float4* __restrict__ out,
                                                     long total, long spatial) {
    long idx = (long)blockIdx.x * blockDim.x + threadIdx.x;
    if (idx >= total) return;
    long b = idx / spatial;
    long s = idx - b * spatial;
    const float* p = vol + b * 4 * spatial + s;
    float4 v;
    v.x = p[0];
    v.y = p[spatial];
    v.z = p[2 * spatial];
    v.w = p[3 * spatial];
    out[idx] = v;
}

template <bool PACKED>
__global__ __launch_bounds__(256) void raymarch_kernel(
        const float* __restrict__ camrot, const float* __restrict__ campos,
        const float* __restrict__ focal, const float* __restrict__ princpt,
        const float* __restrict__ pixelcoords, const float* __restrict__ vol,
        float* __restrict__ out, int B, int H, int W, int D) {
#pragma clang fp contract(off)
    int x = blockIdx.x * blockDim.x + threadIdx.x;
    int y = blockIdx.y * blockDim.y + threadIdx.y;
    int b = blockIdx.z;
    if (x >= W || y >= H) return;

    long pidx = (((long)b * H + y) * W + x) * 2;
    float px = pixelcoords[pidx];
    float py = pixelcoords[pidx + 1];
    const float* R = camrot + b * 9;
    float cpx = campos[b * 3 + 0], cpy = campos[b * 3 + 1], cpz = campos[b * 3 + 2];
    float flx = focal[b * 2 + 0], fly = focal[b * 2 + 1];
    float prx = princpt[b * 2 + 0], pry = princpt[b * 2 + 1];

    // pixel -> camera ray, then world: out[j] = sum_i R[i][j] * r[i]  (camrot^T)
    float rx = (px - prx) / flx;
    float ry = (py - pry) / fly;
    float rz = 1.0f;
    float dx = R[0] * rx + R[3] * ry + R[6] * rz;
    float dy = R[1] * rx + R[4] * ry + R[7] * rz;
    float dz = R[2] * rx + R[5] * ry + R[8] * rz;
    // norm: sum of squares left-to-right, separately rounded; sqrt/div correctly rounded
    float ss = dx * dx;
    ss = ss + dy * dy;
    ss = ss + dz * dz;
    float nrm = sqrtf(ss);
    dx = dx / nrm; dy = dy / nrm; dz = dz / nrm;

    // ray-AABB with [-1,1]^3
    float t1x = (-1.0f - cpx) / dx, t2x = (1.0f - cpx) / dx;
    float t1y = (-1.0f - cpy) / dy, t2y = (1.0f - cpy) / dy;
    float t1z = (-1.0f - cpz) / dz, t2z = (1.0f - cpz) / dz;
    float tmin = fmaxf(fminf(t1x, t2x), fmaxf(fminf(t1y, t2y), fminf(t1z, t2z)));
    float tmax = fminf(fmaxf(t1x, t2x), fminf(fmaxf(t1y, t2y), fmaxf(t1z, t2z)));
    bool hit = tmin < tmax;
    float t0 = fmaxf(hit ? tmin : 0.0f, 0.0f);

    // raypos = campos + raydir * t0 : mul then add, separately rounded
    float posx = cpx + dx * t0;
    float posy = cpy + dy * t0;
    float posz = cpz + dz * t0;
    float stx = dx * DT, sty = dy * DT, stz = dz * DT;

    float accr = 0.0f, accg = 0.0f, accb = 0.0f, alpha = 0.0f;
    float gmax = (float)(D - 1);
    long spatial = (long)D * D * D;
    long zstride = (long)D * D;
    const float4* v4 = reinterpret_cast<const float4*>(vol);
    const float* vb = vol + (long)b * 4 * spatial;
    long b4base = (long)b * spatial;

    bool entered = false;
    for (int s = 0; s < NSTEPS; ++s) {
        bool valid = (posx > -1.0f) && (posx < 1.0f) &&
                     (posy > -1.0f) && (posy < 1.0f) &&
                     (posz > -1.0f) && (posz < 1.0f);
        if (valid) {
            entered = true;
            // g = clip(((pos+1)*0.5)*(n-1), 0, n-1), left-to-right order
            float gx = fminf(fmaxf((posx + 1.0f) * 0.5f * gmax, 0.0f), gmax);
            float gy = fminf(fmaxf((posy + 1.0f) * 0.5f * gmax, 0.0f), gmax);
            float gz = fminf(fmaxf((posz + 1.0f) * 0.5f * gmax, 0.0f), gmax);
            int ix0 = (int)floorf(gx); if (ix0 > D - 2) ix0 = D - 2;
            int iy0 = (int)floorf(gy); if (iy0 > D - 2) iy0 = D - 2;
            int iz0 = (int)floorf(gz); if (iz0 > D - 2) iz0 = D - 2;
            float fx = gx - (float)ix0;
            float fy = gy - (float)iy0;
            float fz = gz - (float)iz0;

            float4 c000, c001, c010, c011, c100, c101, c110, c111;
            if (PACKED) {
                long base = b4base + (long)iz0 * zstride + (long)iy0 * D + ix0;
                c000 = v4[base];
                c001 = v4[base + 1];
                c010 = v4[base + D];
                c011 = v4[base + D + 1];
                c100 = v4[base + zstride];
                c101 = v4[base + zstride + 1];
                c110 = v4[base + zstride + D];
                c111 = v4[base + zstride + D + 1];
            } else {
                long s000 = (long)iz0 * zstride + (long)iy0 * D + ix0;
                #define FETCH(dst, off) { long o_ = (off); \
                    dst.x = vb[o_]; dst.y = vb[o_ + spatial]; \
                    dst.z = vb[o_ + 2 * spatial]; dst.w = vb[o_ + 3 * spatial]; }
                FETCH(c000, s000);
                FETCH(c001, s000 + 1);
                FETCH(c010, s000 + D);
                FETCH(c011, s000 + D + 1);
                FETCH(c100, s000 + zstride);
                FETCH(c101, s000 + zstride + 1);
                FETCH(c110, s000 + zstride + D);
                FETCH(c111, s000 + zstride + D + 1);
                #undef FETCH
            }
            float4 c00 = lerp4(c000, c001, fx);
            float4 c01 = lerp4(c010, c011, fx);
            float4 c10 = lerp4(c100, c101, fx);
            float4 c11 = lerp4(c110, c111, fx);
            float4 c0 = lerp4(c00, c01, fy);
            float4 c1 = lerp4(c10, c11, fy);
            float4 samp = lerp4(c0, c1, fz);

            float contrib = fminf(alpha + samp.w * DT, 1.0f) - alpha;
            accr = accr + samp.x * contrib;
            accg = accg + samp.y * contrib;
            accb = accb + samp.z * contrib;
            alpha = alpha + contrib;
            if (alpha >= 1.0f) break;  // contrib is exactly 0 forever after
        } else if (entered) {
            break;  // convex volume: once exited, never valid again
        }
        posx = posx + stx; posy = posy + sty; posz = posz + stz;
    }

    long hw = (long)H * W;
    long o = (long)b * 4 * hw + (long)y * W + x;
    out[o] = accr;
    out[o + hw] = accg;
    out[o + 2 * hw] = accb;
    out[o + 3 * hw] = alpha;
}

extern "C" void kernel_launch(void* const* d_in, const int* in_sizes, int n_in,
                              void* d_out, int out_size, void* d_ws, size_t ws_size,
                              hipStream_t stream) {
    const float* camrot = (const float*)d_in[0];
    const float* campos = (const float*)d_in[1];
    const float* focal = (const float*)d_in[2];
    const float* princpt = (const float*)d_in[3];
    const float* pixelcoords = (const float*)d_in[4];
    const float* volume = (const float*)d_in[5];
    float* out = (float*)d_out;

    int B = in_sizes[0] / 9;
    long spatial = (long)in_sizes[5] / (B * 4);  // D^3
    int D = (int)lround(cbrt((double)spatial));
    while ((long)D * D * D > spatial) D--;
    while ((long)(D + 1) * (D + 1) * (D + 1) <= spatial) D++;
    long hw = (long)in_sizes[4] / (B * 2);
    int H = (int)lround(sqrt((double)hw));
    int W = H;

    size_t need = (size_t)B * spatial * 4 * sizeof(float);
    dim3 blk(16, 16, 1);
    dim3 grd((W + 15) / 16, (H + 15) / 16, B);

    if (ws_size >= need) {
        long total = (long)B * spatial;
        int th = 256;
        long nb = (total + th - 1) / th;
        repack_kernel<<<dim3((unsigned)nb), dim3(th), 0, stream>>>(volume, (float4*)d_ws,
                                                                   total, spatial);
        raymarch_kernel<true><<<grd, blk, 0, stream>>>(camrot, campos, focal, princpt,
                                                       pixelcoords, (const float*)d_ws,
                                                       out, B, H, W, D);
    } else {
        raymarch_kernel<false><<<grd, blk, 0, stream>>>(camrot, campos, focal, princpt,
                                                        pixelcoords, volume,
                                                        out, B, H, W, D);
    }
}